// Round 13
// baseline (190.652 us; speedup 1.0000x reference)
//
#include <hip/hip_runtime.h>
#include <cstdint>
#include <cstddef>

#define NHEAD 8
#define SLEN 1024

typedef __bf16 bf16x8 __attribute__((ext_vector_type(8)));
typedef float f32x4 __attribute__((ext_vector_type(4)));

__device__ inline unsigned short f2bf(float f) {
    union { float f; unsigned int u; } v; v.f = f;
    unsigned int u = v.u;
    unsigned int rounded = u + 0x7fffu + ((u >> 16) & 1u);
    return (unsigned short)(rounded >> 16);
}

__device__ inline unsigned int pack2(float a, float b) {
    return (unsigned int)f2bf(a) | ((unsigned int)f2bf(b) << 16);
}

// single-instruction bf16 pair pack (RNE, bit-identical to pack2)
__device__ inline unsigned int cvtpk2(float lo, float hi) {
    unsigned int r;
    asm("v_cvt_pk_bf16_f32 %0, %1, %2" : "=v"(r) : "v"(lo), "v"(hi));
    return r;
}

// raw v_exp_f32: computes 2^x. Scores are pre-scaled by log2(e) in qkv's
// Q epilogue, so 2^(s') == exp(s).
__device__ inline float exp2i(float x) {
    float r;
    asm("v_exp_f32 %0, %1" : "=v"(r) : "v"(x));
    return r;
}

// async global->LDS, 16B per lane (dest = uniform base + lane*16)
__device__ inline void gll16(const void* g, void* l) {
    __builtin_amdgcn_global_load_lds(
        (const __attribute__((address_space(1))) unsigned int*)g,
        (__attribute__((address_space(3))) unsigned int*)l,
        16, 0, 0);
}

__device__ inline uint4 cvt8(const float* __restrict__ p) {
    float4 a = *reinterpret_cast<const float4*>(p);
    float4 b = *reinterpret_cast<const float4*>(p + 4);
    uint4 r;
    r.x = pack2(a.x, a.y);
    r.y = pack2(a.z, a.w);
    r.z = pack2(b.x, b.y);
    r.w = pack2(b.z, b.w);
    return r;
}

// ---------------- prep: weights f32->bf16 cast AND mask bit-pack ----------------
// Round-13: X cast removed (again) -- but this time qkv stages A from f32 X
// via REGISTERS with in-register cvt, keeping LDS bf16 (r10's failure was
// the f32 LDS tile: 16-way conflicts + 10% occupancy, NOT the fusion idea).
// prep traffic ~140MB -> ~40MB. This prep structure verified in r10's run.
__global__ __launch_bounds__(256) void prep(
    const float* __restrict__ wq, const float* __restrict__ wk,
    const float* __restrict__ wv, const float* __restrict__ wo,
    const float* __restrict__ mask,
    unsigned short* __restrict__ Wc,
    unsigned long long* __restrict__ bits)
{
    int y = blockIdx.y;
    if (y == 4) {
        int wid = (blockIdx.x * 256 + threadIdx.x) >> 6;
        int lane = threadIdx.x & 63;
        for (int s = 0; s < 16; s++) {
            size_t seg = (size_t)wid * 16 + s;
            float mv = mask[seg * 64 + lane];
            unsigned long long bb = __ballot(mv != 0.0f);
            if (lane == 0) bits[seg] = bb;
        }
        return;
    }
    const float* src = (y == 0) ? wq : (y == 1) ? wk : (y == 2) ? wv : wo;
    unsigned short* dst = Wc + (size_t)y * 262144;
    const int n = 262144;
    int i = (blockIdx.x * 256 + threadIdx.x) * 8;
    if (i + 8 <= n) {
        uint4 v = cvt8(src + i);
        *reinterpret_cast<uint4*>(dst + i) = v;
    }
}

// ---------------- fused QKV projection GEMM (f32 X, reg-staged A + dbuf gll16 B) ----------------
// Round-13: A staged f32 X -> regs (8 float4/thread/tile, coalesced) ->
// cvtpk -> ds_write_b128 into the SAME dbuf bf16 [128][64] layout as r12.
// B unchanged (gll16 dbuf). Per iter: barrier -> writeA(next) (regs landed,
// loaded one iter ago) -> stageB(next) -> loadA(next+1) -> compute. Every
// load gets a full compute phase in flight. A ds_writes hit the b128
// 8-pass bank floor (8 bank-groups x 8 rows).
__global__ __launch_bounds__(256) void qkv_gemm(
    const float* __restrict__ X,
    const unsigned short* __restrict__ Wc,
    const float* __restrict__ bq, const float* __restrict__ bk,
    const float* __restrict__ bv,
    unsigned short* __restrict__ Qb, unsigned short* __restrict__ Kb,
    unsigned short* __restrict__ Vtb)
{
    __shared__ unsigned short SH[32768];   // 64KB: half h at shorts h*16384; A@+0, B@+8192
    const int tid = threadIdx.x;
    const int w = tid >> 6, lane = tid & 63, l15 = lane & 15, quad = lane >> 4;
    const int wm = w & 1, wn = w >> 1;
    const int r0 = blockIdx.x * 128;
    const int ytile = blockIdx.y;
    const int c0 = ytile * 128;
    const unsigned short* Wsel = Wc + (size_t)(ytile >> 2) * 262144;
    const int cw = c0 & 511;

    f32x4 zero = {0.0f, 0.0f, 0.0f, 0.0f};
    f32x4 acc[4][4];
    for (int i = 0; i < 4; i++)
        for (int j = 0; j < 4; j++) acc[i][j] = zero;

    const int lrow = lane >> 3;          // 0..7
    const int lcol = (lane & 7) * 8;     // elems (shorts for B dest, floats for A src)

    float4 arA[4], arB[4];               // staged f32 A data for one tile (32 VGPR)

    auto loadA = [&](int k0) {
        const float* gA = X + (size_t)(r0 + w * 32 + lrow) * 512 + k0 + lcol;
        #pragma unroll
        for (int i = 0; i < 4; i++) {
            arA[i] = *reinterpret_cast<const float4*>(gA + (size_t)i * 8 * 512);
            arB[i] = *reinterpret_cast<const float4*>(gA + (size_t)i * 8 * 512 + 4);
        }
    };
    auto writeA = [&](int hb) {
        unsigned short* lA = SH + hb * 16384 + (w * 32 + lrow) * 64 + lcol;
        #pragma unroll
        for (int i = 0; i < 4; i++) {
            uint4 u;
            u.x = cvtpk2(arA[i].x, arA[i].y);
            u.y = cvtpk2(arA[i].z, arA[i].w);
            u.z = cvtpk2(arB[i].x, arB[i].y);
            u.w = cvtpk2(arB[i].z, arB[i].w);
            *reinterpret_cast<uint4*>(lA + i * 8 * 64) = u;
        }
    };
    auto stageB = [&](int k0, int hb) {
        const unsigned short* gB = Wsel + (size_t)(cw + w * 32 + lrow) * 512 + k0 + lcol;
        unsigned short* lB = SH + hb * 16384 + 8192 + (w * 32) * 64;
        #pragma unroll
        for (int i = 0; i < 4; i++)
            gll16(gB + (size_t)i * 8 * 512, lB + i * 8 * 64);
    };

    // prologue: tile 0 staged, tile 1's A loads in flight
    loadA(0);
    writeA(0);
    stageB(0, 0);
    loadA(64);

    for (int kt = 0; kt < 8; kt++) {
        __syncthreads();                  // buf[kt&1] ready (ds_writes ordered, gll16 drained)
        if (kt < 7) {
            writeA((kt + 1) & 1);         // regs loaded one iter ago -> no stall
            stageB((kt + 1) * 64, (kt + 1) & 1);
            if (kt < 6) loadA((kt + 2) * 64);
        }
        const unsigned short* As = SH + (kt & 1) * 16384;
        const unsigned short* Bs = As + 8192;
        for (int kc = 0; kc < 64; kc += 32) {
            bf16x8 af[4], bfr[4];
            for (int mi = 0; mi < 4; mi++)
                af[mi] = *reinterpret_cast<const bf16x8*>(As + (wm * 64 + mi * 16 + l15) * 64 + kc + quad * 8);
            for (int ni = 0; ni < 4; ni++)
                bfr[ni] = *reinterpret_cast<const bf16x8*>(Bs + (wn * 64 + ni * 16 + l15) * 64 + kc + quad * 8);
            for (int mi = 0; mi < 4; mi++)
                for (int ni = 0; ni < 4; ni++)
                    acc[mi][ni] = __builtin_amdgcn_mfma_f32_16x16x32_bf16(af[mi], bfr[ni], acc[mi][ni], 0, 0, 0);
        }
    }
    __syncthreads();                      // main loop fully done before epilogue overlay

    const int bb = r0 >> 10;
    const int s0 = r0 & 1023;
    unsigned short* Ep = SH;              // epilogue overlay: 128x136 shorts (34.8KB <= 64KB)

    if (ytile < 8) {
        const bool isQ = (ytile < 4);
        const float* bias = isQ ? bq : bk;
        unsigned short* dst = isQ ? Qb : Kb;
        // Q scale = 1/8 * log2(e): attn uses 2^x instead of e^x
        const float scale = isQ ? 0.18033688f : 1.0f;
        const int h0 = cw >> 6;
        for (int mi = 0; mi < 4; mi++) {
            for (int ni = 0; ni < 4; ni++) {
                int col = wn * 64 + ni * 16 + l15;
                float bsv = bias[cw + col];
                for (int r = 0; r < 4; r++) {
                    int s_local = wm * 64 + mi * 16 + quad * 4 + r;
                    Ep[s_local * 136 + col] = f2bf((acc[mi][ni][r] + bsv) * scale);
                }
            }
        }
        __syncthreads();
        for (int p = 0; p < 2; p++) {
            size_t base = (((size_t)(bb * NHEAD + h0 + p)) << 10) + s0;
            for (int i = 0; i < 4; i++) {
                int flat = i * 256 + tid;
                int row = flat >> 3;
                int ch = flat & 7;
                uint4 vv = *reinterpret_cast<const uint4*>(Ep + row * 136 + p * 64 + ch * 8);
                *reinterpret_cast<uint4*>(dst + (base + row) * 64 + ch * 8) = vv;
            }
        }
    } else {
        const int h_base = (c0 - 1024) >> 6;
        for (int p = 0; p < 2; p++) {
            __syncthreads();
            if (wn == p) {
                for (int mi = 0; mi < 4; mi++) {
                    for (int ni = 0; ni < 4; ni++) {
                        int d_local = ni * 16 + l15;
                        float bias = bv[(h_base + p) * 64 + d_local];
                        for (int r = 0; r < 4; r++) {
                            int s_local = wm * 64 + mi * 16 + quad * 4 + r;
                            Ep[d_local * 136 + s_local] = f2bf(acc[mi][ni][r] + bias);
                        }
                    }
                }
            }
            __syncthreads();
            int sidx = (tid & 15) * 8;
            int drow = tid >> 4;
            for (int dg = 0; dg < 4; dg++) {
                int d = dg * 16 + drow;
                size_t dst = ((size_t)(bb * NHEAD + h_base + p) * 64 + d) * 1024 + s0;
                uint4 vv = *reinterpret_cast<const uint4*>(Ep + d * 136 + sidx);
                *reinterpret_cast<uint4*>(Vtb + dst + sidx) = vv;
            }
        }
    }
}

// ---------------- flash attention: LDS-staged K/V, KVBLK=64 (r12 version) ----------------
__global__ __launch_bounds__(256, 4) void attn_kernel(
    const unsigned short* __restrict__ Qb,
    const unsigned short* __restrict__ Kb,
    const unsigned short* __restrict__ Vtb,
    const unsigned long long* __restrict__ Mbits,
    unsigned short* __restrict__ Ob)
{
    __shared__ unsigned short KVs[3 * 64 * 72];       // K @0, V @4608, P @9216

    const int tid = threadIdx.x;
    const int w = tid >> 6, lane = tid & 63, l15 = lane & 15, quad = lane >> 4;
    const int flat = blockIdx.x;
    const int bh = flat & 63;                  // XCD locality: bh%8 = XCD
    const int qt = flat >> 6;                  // 0..15
    const int b = bh >> 3, h = bh & 7;
    const int q = qt * 64 + w * 16 + l15;
    const unsigned short* Qg = Qb + (size_t)bh * SLEN * 64;
    const unsigned short* Kg = Kb + (size_t)bh * SLEN * 64;
    const unsigned short* Vg = Vtb + (size_t)bh * 64 * SLEN;
    const unsigned long long* mrow = Mbits + ((size_t)b * SLEN + q) * 16;
    unsigned short* Ks = KVs;
    unsigned short* Vs = KVs + 4608;
    unsigned short* Prow = KVs + 9216 + (size_t)(w * 16 + l15) * 72;

    bf16x8 bq0 = *reinterpret_cast<const bf16x8*>(Qg + (size_t)q * 64 + quad * 8);
    bf16x8 bq1 = *reinterpret_cast<const bf16x8*>(Qg + (size_t)q * 64 + 32 + quad * 8);

    f32x4 zero = {0.0f, 0.0f, 0.0f, 0.0f};
    f32x4 Oacc[4];
    for (int nd = 0; nd < 4; nd++) Oacc[nd] = zero;
    float lsum0 = 0.0f, lsum1 = 0.0f;

    // cooperative staging pattern: thread covers rows srow, srow+32; 16B cols
    const int srow = tid >> 3;                 // 0..31
    const int sc8 = (tid & 7) * 8;             // shorts

    // prologue: load tile 0 into registers
    uint4 kr0, kr1, vr0, vr1;
    {
        const unsigned short* kp = Kg + (size_t)srow * 64 + sc8;
        kr0 = *reinterpret_cast<const uint4*>(kp);
        kr1 = *reinterpret_cast<const uint4*>(kp + 32 * 64);
        const unsigned short* vp = Vg + (size_t)srow * SLEN + sc8;
        vr0 = *reinterpret_cast<const uint4*>(vp);
        vr1 = *reinterpret_cast<const uint4*>(vp + (size_t)32 * SLEN);
    }

    for (int kt = 0; kt < 16; kt++) {
        // write staged tile (compiler inserts vmcnt wait on kr/vr)
        *reinterpret_cast<uint4*>(Ks + srow * 72 + sc8) = kr0;
        *reinterpret_cast<uint4*>(Ks + (srow + 32) * 72 + sc8) = kr1;
        *reinterpret_cast<uint4*>(Vs + srow * 72 + sc8) = vr0;
        *reinterpret_cast<uint4*>(Vs + (srow + 32) * 72 + sc8) = vr1;
        __syncthreads();

        // issue next tile's global loads NOW; they fly under this compute
        if (kt < 15) {
            int k0n = (kt + 1) * 64;
            const unsigned short* kp = Kg + (size_t)(k0n + srow) * 64 + sc8;
            kr0 = *reinterpret_cast<const uint4*>(kp);
            kr1 = *reinterpret_cast<const uint4*>(kp + 32 * 64);
            const unsigned short* vp = Vg + (size_t)srow * SLEN + k0n + sc8;
            vr0 = *reinterpret_cast<const uint4*>(vp);
            vr1 = *reinterpret_cast<const uint4*>(vp + (size_t)32 * SLEN);
        }

        // S^T = K Q^T over 64 keys (4 subtiles of 16), K from LDS
        f32x4 st[4];
        for (int ni = 0; ni < 4; ni++) {
            const unsigned short* kp = Ks + (ni * 16 + l15) * 72 + quad * 8;
            bf16x8 ka0 = *reinterpret_cast<const bf16x8*>(kp);
            bf16x8 ka1 = *reinterpret_cast<const bf16x8*>(kp + 32);
            f32x4 z = zero;
            z = __builtin_amdgcn_mfma_f32_16x16x32_bf16(ka0, bq0, z, 0, 0, 0);
            z = __builtin_amdgcn_mfma_f32_16x16x32_bf16(ka1, bq1, z, 0, 0, 0);
            st[ni] = z;
        }

        // p = masked ? 0 : 2^(s'); accumulate l; pack P^T row
        unsigned long long mv = mrow[kt] >> (quad * 4);
        unsigned int lo = (unsigned int)mv, hi = (unsigned int)(mv >> 32);
        for (int ni = 0; ni < 4; ni++) {
            unsigned int word = (ni & 2) ? hi : lo;
            int sh = (ni & 1) ? 16 : 0;
            float p0 = ((word >> (sh + 0)) & 1u) ? 0.0f : exp2i(st[ni][0]);
            float p1 = ((word >> (sh + 1)) & 1u) ? 0.0f : exp2i(st[ni][1]);
            float p2 = ((word >> (sh + 2)) & 1u) ? 0.0f : exp2i(st[ni][2]);
            float p3 = ((word >> (sh + 3)) & 1u) ? 0.0f : exp2i(st[ni][3]);
            lsum0 += (p0 + p1);
            lsum1 += (p2 + p3);
            uint2 pk;
            pk.x = cvtpk2(p0, p1);
            pk.y = cvtpk2(p2, p3);
            *reinterpret_cast<uint2*>(Prow + ni * 16 + quad * 4) = pk;
        }

        // O^T += V^T P^T (2 K=32 steps over 64 keys), V from LDS
        bf16x8 pb0 = *reinterpret_cast<const bf16x8*>(Prow + quad * 8);
        bf16x8 pb1 = *reinterpret_cast<const bf16x8*>(Prow + 32 + quad * 8);
        for (int nd = 0; nd < 4; nd++) {
            const unsigned short* vb = Vs + (nd * 16 + l15) * 72 + quad * 8;
            bf16x8 va0 = *reinterpret_cast<const bf16x8*>(vb);
            bf16x8 va1 = *reinterpret_cast<const bf16x8*>(vb + 32);
            Oacc[nd] = __builtin_amdgcn_mfma_f32_16x16x32_bf16(va0, pb0, Oacc[nd], 0, 0, 0);
            Oacc[nd] = __builtin_amdgcn_mfma_f32_16x16x32_bf16(va1, pb1, Oacc[nd], 0, 0, 0);
        }
        __syncthreads();
    }

    // single final normalization for this lane's q row
    float l = lsum0 + lsum1;
    l += __shfl_xor(l, 16);
    l += __shfl_xor(l, 32);
    float inv = (l > 0.0f) ? (1.0f / l) : 0.0f;
    for (int nd = 0; nd < 4; nd++) {
        uint2 o;
        o.x = cvtpk2(Oacc[nd][0] * inv, Oacc[nd][1] * inv);
        o.y = cvtpk2(Oacc[nd][2] * inv, Oacc[nd][3] * inv);
        *reinterpret_cast<uint2*>(Ob + ((size_t)(b * SLEN + q)) * 512 + h * 64 + nd * 16 + quad * 4) = o;
    }
}

// ---------------- output projection GEMM (64x128 tile, BK=64, global_load_lds) ----------------
__global__ __launch_bounds__(256) void out_gemm(
    const unsigned short* __restrict__ Ob,
    const unsigned short* __restrict__ Wob,
    const float* __restrict__ bo,
    float* __restrict__ out)
{
    __shared__ unsigned short As[64 * 64 + 128 * 64];   // A[64][64] @0 (8KB), B[128][64] @4096 (16KB)
    unsigned short* Bs = As + 64 * 64;
    const int tid = threadIdx.x;
    const int w = tid >> 6, lane = tid & 63, l15 = lane & 15, quad = lane >> 4;
    const int r0 = blockIdx.x * 64;
    const int c0 = blockIdx.y * 128;

    f32x4 zero = {0.0f, 0.0f, 0.0f, 0.0f};
    f32x4 acc[4][2];
    for (int i = 0; i < 4; i++)
        for (int j = 0; j < 2; j++) acc[i][j] = zero;

    const int lrow = lane >> 3;          // 0..7
    const int lcol = (lane & 7) * 8;     // shorts

    for (int k0 = 0; k0 < 512; k0 += 64) {
        // A: 64 rows; wave w stages rows w*16 + i*8 + lrow, i<2
        const unsigned short* gA = Ob + (size_t)(r0 + w * 16 + lrow) * 512 + k0 + lcol;
        unsigned short* lA = As + (w * 16) * 64;
        #pragma unroll
        for (int i = 0; i < 2; i++)
            gll16(gA + (size_t)i * 8 * 512, lA + i * 8 * 64);
        // B: 128 rows; wave w stages rows w*32 + i*8 + lrow, i<4
        const unsigned short* gB = Wob + (size_t)(c0 + w * 32 + lrow) * 512 + k0 + lcol;
        unsigned short* lB = Bs + (w * 32) * 64;
        #pragma unroll
        for (int i = 0; i < 4; i++)
            gll16(gB + (size_t)i * 8 * 512, lB + i * 8 * 64);
        __syncthreads();
        for (int kc = 0; kc < 64; kc += 32) {
            bf16x8 af[4], bfr[2];
            for (int mi = 0; mi < 4; mi++)
                af[mi] = *reinterpret_cast<const bf16x8*>(As + (mi * 16 + l15) * 64 + kc + quad * 8);
            for (int ni = 0; ni < 2; ni++)
                bfr[ni] = *reinterpret_cast<const bf16x8*>(Bs + (w * 32 + ni * 16 + l15) * 64 + kc + quad * 8);
            for (int mi = 0; mi < 4; mi++)
                for (int ni = 0; ni < 2; ni++)
                    acc[mi][ni] = __builtin_amdgcn_mfma_f32_16x16x32_bf16(af[mi], bfr[ni], acc[mi][ni], 0, 0, 0);
        }
        __syncthreads();
    }

    for (int mi = 0; mi < 4; mi++) {
        int grow_base = r0 + mi * 16 + quad * 4;
        for (int ni = 0; ni < 2; ni++) {
            int gcol = c0 + w * 32 + ni * 16 + l15;
            float bias = bo[gcol];
            for (int r = 0; r < 4; r++) {
                int grow = grow_base + r;
                out[(size_t)grow * 512 + gcol] = acc[mi][ni][r] + bias;
            }
        }
    }
}

extern "C" void kernel_launch(void* const* d_in, const int* in_sizes, int n_in,
                              void* d_out, int out_size, void* d_ws, size_t ws_size,
                              hipStream_t stream) {
    (void)in_sizes; (void)n_in; (void)out_size; (void)ws_size;
    const float* x    = (const float*)d_in[0];
    const float* mask = (const float*)d_in[1];
    const float* wq   = (const float*)d_in[2];
    const float* bq   = (const float*)d_in[3];
    const float* wk   = (const float*)d_in[4];
    const float* bk   = (const float*)d_in[5];
    const float* wv   = (const float*)d_in[6];
    const float* bv   = (const float*)d_in[7];
    const float* wo   = (const float*)d_in[8];
    const float* bo   = (const float*)d_in[9];
    float* out = (float*)d_out;

    char* ws = (char*)d_ws;
    unsigned short* Qb   = (unsigned short*)(ws);                  // 8 MiB (B,H,S,64)
    unsigned short* Kb   = (unsigned short*)(ws + 8388608);        // 8 MiB (B,H,S,64)
    unsigned short* Vtb  = (unsigned short*)(ws + 16777216);       // 8 MiB (B,H,64,S)
    unsigned short* Obuf = (unsigned short*)(ws + 25165824);       // 8 MiB
    unsigned short* Wc   = (unsigned short*)(ws + 33554432);       // 2 MiB bf16 weights
    unsigned long long* Mbits = (unsigned long long*)(ws + 35651584); // 1 MiB

    prep<<<dim3(2048, 5), 256, 0, stream>>>(wq, wk, wv, wo, mask, Wc, Mbits);
    qkv_gemm<<<dim3(64, 12), 256, 0, stream>>>(x, Wc, bq, bk, bv, Qb, Kb, Vtb);
    attn_kernel<<<dim3(1024), 256, 0, stream>>>(Qb, Kb, Vtb, Mbits, Obuf);
    out_gemm<<<dim3(128, 4), 256, 0, stream>>>(Obuf, Wc + 3 * 262144, bo, out);
}

// Round 14
// 179.846 us; speedup vs baseline: 1.0601x; 1.0601x over previous
//
#include <hip/hip_runtime.h>
#include <cstdint>
#include <cstddef>

#define NHEAD 8
#define SLEN 1024

typedef __bf16 bf16x8 __attribute__((ext_vector_type(8)));
typedef float f32x4 __attribute__((ext_vector_type(4)));

__device__ inline unsigned short f2bf(float f) {
    union { float f; unsigned int u; } v; v.f = f;
    unsigned int u = v.u;
    unsigned int rounded = u + 0x7fffu + ((u >> 16) & 1u);
    return (unsigned short)(rounded >> 16);
}

__device__ inline unsigned int pack2(float a, float b) {
    return (unsigned int)f2bf(a) | ((unsigned int)f2bf(b) << 16);
}

// single-instruction bf16 pair pack (RNE, bit-identical to pack2)
__device__ inline unsigned int cvtpk2(float lo, float hi) {
    unsigned int r;
    asm("v_cvt_pk_bf16_f32 %0, %1, %2" : "=v"(r) : "v"(lo), "v"(hi));
    return r;
}

// raw v_exp_f32: computes 2^x. Scores are pre-scaled by log2(e) in qkv's
// Q epilogue, so 2^(s') == exp(s).
__device__ inline float exp2i(float x) {
    float r;
    asm("v_exp_f32 %0, %1" : "=v"(r) : "v"(x));
    return r;
}

// async global->LDS, 16B per lane (dest = uniform base + lane*16)
__device__ inline void gll16(const void* g, void* l) {
    __builtin_amdgcn_global_load_lds(
        (const __attribute__((address_space(1))) unsigned int*)g,
        (__attribute__((address_space(3))) unsigned int*)l,
        16, 0, 0);
}

__device__ inline uint4 cvt8(const float* __restrict__ p) {
    float4 a = *reinterpret_cast<const float4*>(p);
    float4 b = *reinterpret_cast<const float4*>(p + 4);
    uint4 r;
    r.x = pack2(a.x, a.y);
    r.y = pack2(a.z, a.w);
    r.z = pack2(b.x, b.y);
    r.w = pack2(b.z, b.w);
    return r;
}

// ---------------- prep: f32->bf16 cast (X + 4 weights) AND mask bit-pack ----------------
// r13 lesson (final): keep the X cast HERE. Both fusion variants (r9/r10
// lds-direct f32, r13 reg-staged) were net-negative: the cast-once pattern
// is cheaper than re-reading f32 X in the GEMM. Branch closed.
__global__ __launch_bounds__(256) void prep(
    const float* __restrict__ X,
    const float* __restrict__ wq, const float* __restrict__ wk,
    const float* __restrict__ wv, const float* __restrict__ wo,
    const float* __restrict__ mask,
    unsigned short* __restrict__ Xb, unsigned short* __restrict__ Wc,
    unsigned long long* __restrict__ bits)
{
    int y = blockIdx.y;
    if (y == 5) {
        int wid = (blockIdx.x * 256 + threadIdx.x) >> 6;
        int lane = threadIdx.x & 63;
        for (int s = 0; s < 16; s++) {
            size_t seg = (size_t)wid * 16 + s;
            float mv = mask[seg * 64 + lane];
            unsigned long long bb = __ballot(mv != 0.0f);
            if (lane == 0) bits[seg] = bb;
        }
        return;
    }
    const float* src;
    unsigned short* dst;
    int n;
    if (y == 0) { src = X;  dst = Xb; n = 8192 * 512; }
    else {
        src = (y == 1) ? wq : (y == 2) ? wk : (y == 3) ? wv : wo;
        dst = Wc + (size_t)(y - 1) * 262144;
        n = 262144;
    }
    int i = (blockIdx.x * 256 + threadIdx.x) * 8;
    if (i + 8 <= n) {
        uint4 v = cvt8(src + i);
        *reinterpret_cast<uint4*>(dst + i) = v;
    }
}

// ---------------- fused QKV projection GEMM (bf16, BK=64, DBUF global_load_lds) ----------------
// r12 version (verified best): single-buffered global_load_lds cannot
// pipeline (load -> vmcnt(0) drain -> compute serialized); double-buffering
// lets the next tile's loads fly under the current tile's MFMAs.
__global__ __launch_bounds__(256) void qkv_gemm(
    const unsigned short* __restrict__ Xb,
    const unsigned short* __restrict__ Wc,
    const float* __restrict__ bq, const float* __restrict__ bk,
    const float* __restrict__ bv,
    unsigned short* __restrict__ Qb, unsigned short* __restrict__ Kb,
    unsigned short* __restrict__ Vtb)
{
    __shared__ unsigned short SH[32768];   // 64KB: half h at shorts h*16384; A@+0, B@+8192
    const int tid = threadIdx.x;
    const int w = tid >> 6, lane = tid & 63, l15 = lane & 15, quad = lane >> 4;
    const int wm = w & 1, wn = w >> 1;
    const int r0 = blockIdx.x * 128;
    const int ytile = blockIdx.y;
    const int c0 = ytile * 128;
    const unsigned short* Wsel = Wc + (size_t)(ytile >> 2) * 262144;
    const int cw = c0 & 511;

    f32x4 zero = {0.0f, 0.0f, 0.0f, 0.0f};
    f32x4 acc[4][4];
    for (int i = 0; i < 4; i++)
        for (int j = 0; j < 4; j++) acc[i][j] = zero;

    const int lrow = lane >> 3;          // 0..7
    const int lcol = (lane & 7) * 8;     // shorts

    auto stage = [&](int k0, int hb) {
        const unsigned short* gA = Xb + (size_t)(r0 + w * 32 + lrow) * 512 + k0 + lcol;
        const unsigned short* gB = Wsel + (size_t)(cw + w * 32 + lrow) * 512 + k0 + lcol;
        unsigned short* lA = SH + hb * 16384 + (w * 32) * 64;
        unsigned short* lB = SH + hb * 16384 + 8192 + (w * 32) * 64;
        #pragma unroll
        for (int i = 0; i < 4; i++) {
            gll16(gA + (size_t)i * 8 * 512, lA + i * 8 * 64);
            gll16(gB + (size_t)i * 8 * 512, lB + i * 8 * 64);
        }
    };

    stage(0, 0);                          // prologue: tile 0 in flight
    for (int kt = 0; kt < 8; kt++) {
        __syncthreads();                  // buf[kt&1] loads drained; prior readers done
        if (kt < 7) stage((kt + 1) * 64, (kt + 1) & 1);   // next tile flies under compute
        const unsigned short* As = SH + (kt & 1) * 16384;
        const unsigned short* Bs = As + 8192;
        for (int kc = 0; kc < 64; kc += 32) {
            bf16x8 af[4], bfr[4];
            for (int mi = 0; mi < 4; mi++)
                af[mi] = *reinterpret_cast<const bf16x8*>(As + (wm * 64 + mi * 16 + l15) * 64 + kc + quad * 8);
            for (int ni = 0; ni < 4; ni++)
                bfr[ni] = *reinterpret_cast<const bf16x8*>(Bs + (wn * 64 + ni * 16 + l15) * 64 + kc + quad * 8);
            for (int mi = 0; mi < 4; mi++)
                for (int ni = 0; ni < 4; ni++)
                    acc[mi][ni] = __builtin_amdgcn_mfma_f32_16x16x32_bf16(af[mi], bfr[ni], acc[mi][ni], 0, 0, 0);
        }
    }
    __syncthreads();                      // main loop fully done before epilogue overlay

    const int bb = r0 >> 10;
    const int s0 = r0 & 1023;
    unsigned short* Ep = SH;              // epilogue overlay: 128x136 shorts (34.8KB <= 64KB)

    if (ytile < 8) {
        const bool isQ = (ytile < 4);
        const float* bias = isQ ? bq : bk;
        unsigned short* dst = isQ ? Qb : Kb;
        // Q scale = 1/8 * log2(e): attn uses 2^x instead of e^x
        const float scale = isQ ? 0.18033688f : 1.0f;
        const int h0 = cw >> 6;
        for (int mi = 0; mi < 4; mi++) {
            for (int ni = 0; ni < 4; ni++) {
                int col = wn * 64 + ni * 16 + l15;
                float bsv = bias[cw + col];
                for (int r = 0; r < 4; r++) {
                    int s_local = wm * 64 + mi * 16 + quad * 4 + r;
                    Ep[s_local * 136 + col] = f2bf((acc[mi][ni][r] + bsv) * scale);
                }
            }
        }
        __syncthreads();
        for (int p = 0; p < 2; p++) {
            size_t base = (((size_t)(bb * NHEAD + h0 + p)) << 10) + s0;
            for (int i = 0; i < 4; i++) {
                int flat = i * 256 + tid;
                int row = flat >> 3;
                int ch = flat & 7;
                uint4 vv = *reinterpret_cast<const uint4*>(Ep + row * 136 + p * 64 + ch * 8);
                *reinterpret_cast<uint4*>(dst + (base + row) * 64 + ch * 8) = vv;
            }
        }
    } else {
        const int h_base = (c0 - 1024) >> 6;
        for (int p = 0; p < 2; p++) {
            __syncthreads();
            if (wn == p) {
                for (int mi = 0; mi < 4; mi++) {
                    for (int ni = 0; ni < 4; ni++) {
                        int d_local = ni * 16 + l15;
                        float bias = bv[(h_base + p) * 64 + d_local];
                        for (int r = 0; r < 4; r++) {
                            int s_local = wm * 64 + mi * 16 + quad * 4 + r;
                            Ep[d_local * 136 + s_local] = f2bf(acc[mi][ni][r] + bias);
                        }
                    }
                }
            }
            __syncthreads();
            int sidx = (tid & 15) * 8;
            int drow = tid >> 4;
            for (int dg = 0; dg < 4; dg++) {
                int d = dg * 16 + drow;
                size_t dst = ((size_t)(bb * NHEAD + h_base + p) * 64 + d) * 1024 + s0;
                uint4 vv = *reinterpret_cast<const uint4*>(Ep + d * 136 + sidx);
                *reinterpret_cast<uint4*>(Vtb + dst + sidx) = vv;
            }
        }
    }
}

// ---------------- flash attention: LDS-staged K/V, KVBLK=64 (r12 version) ----------------
__global__ __launch_bounds__(256, 4) void attn_kernel(
    const unsigned short* __restrict__ Qb,
    const unsigned short* __restrict__ Kb,
    const unsigned short* __restrict__ Vtb,
    const unsigned long long* __restrict__ Mbits,
    unsigned short* __restrict__ Ob)
{
    __shared__ unsigned short KVs[3 * 64 * 72];       // K @0, V @4608, P @9216

    const int tid = threadIdx.x;
    const int w = tid >> 6, lane = tid & 63, l15 = lane & 15, quad = lane >> 4;
    const int flat = blockIdx.x;
    const int bh = flat & 63;                  // XCD locality: bh%8 = XCD
    const int qt = flat >> 6;                  // 0..15
    const int b = bh >> 3, h = bh & 7;
    const int q = qt * 64 + w * 16 + l15;
    const unsigned short* Qg = Qb + (size_t)bh * SLEN * 64;
    const unsigned short* Kg = Kb + (size_t)bh * SLEN * 64;
    const unsigned short* Vg = Vtb + (size_t)bh * 64 * SLEN;
    const unsigned long long* mrow = Mbits + ((size_t)b * SLEN + q) * 16;
    unsigned short* Ks = KVs;
    unsigned short* Vs = KVs + 4608;
    unsigned short* Prow = KVs + 9216 + (size_t)(w * 16 + l15) * 72;

    bf16x8 bq0 = *reinterpret_cast<const bf16x8*>(Qg + (size_t)q * 64 + quad * 8);
    bf16x8 bq1 = *reinterpret_cast<const bf16x8*>(Qg + (size_t)q * 64 + 32 + quad * 8);

    f32x4 zero = {0.0f, 0.0f, 0.0f, 0.0f};
    f32x4 Oacc[4];
    for (int nd = 0; nd < 4; nd++) Oacc[nd] = zero;
    float lsum0 = 0.0f, lsum1 = 0.0f;

    // cooperative staging pattern: thread covers rows srow, srow+32; 16B cols
    const int srow = tid >> 3;                 // 0..31
    const int sc8 = (tid & 7) * 8;             // shorts

    // prologue: load tile 0 into registers
    uint4 kr0, kr1, vr0, vr1;
    {
        const unsigned short* kp = Kg + (size_t)srow * 64 + sc8;
        kr0 = *reinterpret_cast<const uint4*>(kp);
        kr1 = *reinterpret_cast<const uint4*>(kp + 32 * 64);
        const unsigned short* vp = Vg + (size_t)srow * SLEN + sc8;
        vr0 = *reinterpret_cast<const uint4*>(vp);
        vr1 = *reinterpret_cast<const uint4*>(vp + (size_t)32 * SLEN);
    }

    for (int kt = 0; kt < 16; kt++) {
        // write staged tile (compiler inserts vmcnt wait on kr/vr)
        *reinterpret_cast<uint4*>(Ks + srow * 72 + sc8) = kr0;
        *reinterpret_cast<uint4*>(Ks + (srow + 32) * 72 + sc8) = kr1;
        *reinterpret_cast<uint4*>(Vs + srow * 72 + sc8) = vr0;
        *reinterpret_cast<uint4*>(Vs + (srow + 32) * 72 + sc8) = vr1;
        __syncthreads();

        // issue next tile's global loads NOW; they fly under this compute
        if (kt < 15) {
            int k0n = (kt + 1) * 64;
            const unsigned short* kp = Kg + (size_t)(k0n + srow) * 64 + sc8;
            kr0 = *reinterpret_cast<const uint4*>(kp);
            kr1 = *reinterpret_cast<const uint4*>(kp + 32 * 64);
            const unsigned short* vp = Vg + (size_t)srow * SLEN + k0n + sc8;
            vr0 = *reinterpret_cast<const uint4*>(vp);
            vr1 = *reinterpret_cast<const uint4*>(vp + (size_t)32 * SLEN);
        }

        // S^T = K Q^T over 64 keys (4 subtiles of 16), K from LDS
        f32x4 st[4];
        for (int ni = 0; ni < 4; ni++) {
            const unsigned short* kp = Ks + (ni * 16 + l15) * 72 + quad * 8;
            bf16x8 ka0 = *reinterpret_cast<const bf16x8*>(kp);
            bf16x8 ka1 = *reinterpret_cast<const bf16x8*>(kp + 32);
            f32x4 z = zero;
            z = __builtin_amdgcn_mfma_f32_16x16x32_bf16(ka0, bq0, z, 0, 0, 0);
            z = __builtin_amdgcn_mfma_f32_16x16x32_bf16(ka1, bq1, z, 0, 0, 0);
            st[ni] = z;
        }

        // p = masked ? 0 : 2^(s'); accumulate l; pack P^T row
        unsigned long long mv = mrow[kt] >> (quad * 4);
        unsigned int lo = (unsigned int)mv, hi = (unsigned int)(mv >> 32);
        for (int ni = 0; ni < 4; ni++) {
            unsigned int word = (ni & 2) ? hi : lo;
            int sh = (ni & 1) ? 16 : 0;
            float p0 = ((word >> (sh + 0)) & 1u) ? 0.0f : exp2i(st[ni][0]);
            float p1 = ((word >> (sh + 1)) & 1u) ? 0.0f : exp2i(st[ni][1]);
            float p2 = ((word >> (sh + 2)) & 1u) ? 0.0f : exp2i(st[ni][2]);
            float p3 = ((word >> (sh + 3)) & 1u) ? 0.0f : exp2i(st[ni][3]);
            lsum0 += (p0 + p1);
            lsum1 += (p2 + p3);
            uint2 pk;
            pk.x = cvtpk2(p0, p1);
            pk.y = cvtpk2(p2, p3);
            *reinterpret_cast<uint2*>(Prow + ni * 16 + quad * 4) = pk;
        }

        // O^T += V^T P^T (2 K=32 steps over 64 keys), V from LDS
        bf16x8 pb0 = *reinterpret_cast<const bf16x8*>(Prow + quad * 8);
        bf16x8 pb1 = *reinterpret_cast<const bf16x8*>(Prow + 32 + quad * 8);
        for (int nd = 0; nd < 4; nd++) {
            const unsigned short* vb = Vs + (nd * 16 + l15) * 72 + quad * 8;
            bf16x8 va0 = *reinterpret_cast<const bf16x8*>(vb);
            bf16x8 va1 = *reinterpret_cast<const bf16x8*>(vb + 32);
            Oacc[nd] = __builtin_amdgcn_mfma_f32_16x16x32_bf16(va0, pb0, Oacc[nd], 0, 0, 0);
            Oacc[nd] = __builtin_amdgcn_mfma_f32_16x16x32_bf16(va1, pb1, Oacc[nd], 0, 0, 0);
        }
        __syncthreads();
    }

    // single final normalization for this lane's q row
    float l = lsum0 + lsum1;
    l += __shfl_xor(l, 16);
    l += __shfl_xor(l, 32);
    float inv = (l > 0.0f) ? (1.0f / l) : 0.0f;
    for (int nd = 0; nd < 4; nd++) {
        uint2 o;
        o.x = cvtpk2(Oacc[nd][0] * inv, Oacc[nd][1] * inv);
        o.y = cvtpk2(Oacc[nd][2] * inv, Oacc[nd][3] * inv);
        *reinterpret_cast<uint2*>(Ob + ((size_t)(b * SLEN + q)) * 512 + h * 64 + nd * 16 + quad * 4) = o;
    }
}

// ---------------- output projection GEMM (64x128 tile, DBUF global_load_lds) ----------------
// Round-14: same defect r12 fixed in qkv -- single-buffered gll16 serializes
// every K-step (load -> vmcnt(0) drain -> compute). Double-buffer the 24KB
// staging halves (48KB total, 2 blocks/CU = grid's 2/CU, not binding);
// tile k+1's loads fly under tile k's MFMAs.
__global__ __launch_bounds__(256) void out_gemm(
    const unsigned short* __restrict__ Ob,
    const unsigned short* __restrict__ Wob,
    const float* __restrict__ bo,
    float* __restrict__ out)
{
    __shared__ unsigned short SH[24576];   // 48KB: half h at shorts h*12288; A[64][64]@+0, B[128][64]@+4096
    const int tid = threadIdx.x;
    const int w = tid >> 6, lane = tid & 63, l15 = lane & 15, quad = lane >> 4;
    const int r0 = blockIdx.x * 64;
    const int c0 = blockIdx.y * 128;

    f32x4 zero = {0.0f, 0.0f, 0.0f, 0.0f};
    f32x4 acc[4][2];
    for (int i = 0; i < 4; i++)
        for (int j = 0; j < 2; j++) acc[i][j] = zero;

    const int lrow = lane >> 3;          // 0..7
    const int lcol = (lane & 7) * 8;     // shorts

    auto stage = [&](int k0, int hb) {
        const unsigned short* gA = Ob + (size_t)(r0 + w * 16 + lrow) * 512 + k0 + lcol;
        unsigned short* lA = SH + hb * 12288 + (w * 16) * 64;
        #pragma unroll
        for (int i = 0; i < 2; i++)
            gll16(gA + (size_t)i * 8 * 512, lA + i * 8 * 64);
        const unsigned short* gB = Wob + (size_t)(c0 + w * 32 + lrow) * 512 + k0 + lcol;
        unsigned short* lB = SH + hb * 12288 + 4096 + (w * 32) * 64;
        #pragma unroll
        for (int i = 0; i < 4; i++)
            gll16(gB + (size_t)i * 8 * 512, lB + i * 8 * 64);
    };

    stage(0, 0);
    for (int kt = 0; kt < 8; kt++) {
        __syncthreads();                  // buf[kt&1] drained; prior readers done
        if (kt < 7) stage((kt + 1) * 64, (kt + 1) & 1);
        const unsigned short* As = SH + (kt & 1) * 12288;
        const unsigned short* Bs = As + 4096;
        for (int kc = 0; kc < 64; kc += 32) {
            bf16x8 af[4], bfr[2];
            for (int mi = 0; mi < 4; mi++)
                af[mi] = *reinterpret_cast<const bf16x8*>(As + (mi * 16 + l15) * 64 + kc + quad * 8);
            for (int ni = 0; ni < 2; ni++)
                bfr[ni] = *reinterpret_cast<const bf16x8*>(Bs + (w * 32 + ni * 16 + l15) * 64 + kc + quad * 8);
            for (int mi = 0; mi < 4; mi++)
                for (int ni = 0; ni < 2; ni++)
                    acc[mi][ni] = __builtin_amdgcn_mfma_f32_16x16x32_bf16(af[mi], bfr[ni], acc[mi][ni], 0, 0, 0);
        }
    }

    for (int mi = 0; mi < 4; mi++) {
        int grow_base = r0 + mi * 16 + quad * 4;
        for (int ni = 0; ni < 2; ni++) {
            int gcol = c0 + w * 32 + ni * 16 + l15;
            float bias = bo[gcol];
            for (int r = 0; r < 4; r++) {
                int grow = grow_base + r;
                out[(size_t)grow * 512 + gcol] = acc[mi][ni][r] + bias;
            }
        }
    }
}

extern "C" void kernel_launch(void* const* d_in, const int* in_sizes, int n_in,
                              void* d_out, int out_size, void* d_ws, size_t ws_size,
                              hipStream_t stream) {
    (void)in_sizes; (void)n_in; (void)out_size; (void)ws_size;
    const float* x    = (const float*)d_in[0];
    const float* mask = (const float*)d_in[1];
    const float* wq   = (const float*)d_in[2];
    const float* bq   = (const float*)d_in[3];
    const float* wk   = (const float*)d_in[4];
    const float* bk   = (const float*)d_in[5];
    const float* wv   = (const float*)d_in[6];
    const float* bv   = (const float*)d_in[7];
    const float* wo   = (const float*)d_in[8];
    const float* bo   = (const float*)d_in[9];
    float* out = (float*)d_out;

    char* ws = (char*)d_ws;
    unsigned short* Qb   = (unsigned short*)(ws);                  // 8 MiB (B,H,S,64)
    unsigned short* Kb   = (unsigned short*)(ws + 8388608);        // 8 MiB (B,H,S,64)
    unsigned short* Vtb  = (unsigned short*)(ws + 16777216);       // 8 MiB (B,H,64,S)
    unsigned short* XO   = (unsigned short*)(ws + 25165824);       // 8 MiB: Xb then Obuf
    unsigned short* Wc   = (unsigned short*)(ws + 33554432);       // 2 MiB bf16 weights
    unsigned long long* Mbits = (unsigned long long*)(ws + 35651584); // 1 MiB

    prep<<<dim3(2048, 6), 256, 0, stream>>>(x, wq, wk, wv, wo, mask, XO, Wc, Mbits);
    qkv_gemm<<<dim3(64, 12), 256, 0, stream>>>(XO, Wc, bq, bk, bv, Qb, Kb, Vtb);
    attn_kernel<<<dim3(1024), 256, 0, stream>>>(Qb, Kb, Vtb, Mbits, XO /*Obuf*/);
    out_gemm<<<dim3(128, 4), 256, 0, stream>>>(XO /*Obuf*/, Wc + 3 * 262144, bo, out);
}